// Round 9
// baseline (516.620 us; speedup 1.0000x reference)
//
#include <hip/hip_runtime.h>
#include <math.h>

// Problem constants
#define Bsz  4096
#define Tlen 512
#define NE   30
#define NIN  5
#define HD10 10
#define B10  (Bsz*HD10)   // per-head plane: 40960 floats

typedef _Float16 h2v  __attribute__((ext_vector_type(2)));
typedef _Float16 f16x8 __attribute__((ext_vector_type(8)));
typedef float    f32x4 __attribute__((ext_vector_type(4)));

__device__ __forceinline__ float fexp2(float x){ return __builtin_amdgcn_exp2f(x); }
__device__ __forceinline__ float frcp (float x){ return __builtin_amdgcn_rcpf(x); }
#define L2E 1.4426950408889634f

__device__ __forceinline__ void loadarr32(float arr[32], const float* bufrow){
  const float4* p4 = (const float4*)bufrow;
  #pragma unroll
  for (int q4=0;q4<8;q4++){ float4 vv=p4[q4]; arr[4*q4]=vv.x; arr[4*q4+1]=vv.y; arr[4*q4+2]=vv.z; arr[4*q4+3]=vv.w; }
}

// ---------------------------------------------------------------------------
// Kernel 1 (MFMA LSTM, R9: occupancy): fused x-proj + recurrence + qkv.
// R8 counters: Occupancy 5.9% (1 block/CU, grid=256=CU count) -> both waves
// stall together at every barrier/LDS wait; ~800 of 1250 cyc/step is exposed
// stall. R9: 512 blocks x 8 batches -> 2 blocks/CU interleave their stalls.
// Per-wave instruction cost is UNCHANGED (activation count is per-lane, not
// per-valid-batch); B-frag cols 8..15 are pad (finite garbage, never stored).
// Fragment layouts (m89/m120-verified, R7-proven):
//   A[m=lane&15][k=(lane>>4)*8+j], B[k=(lane>>4)*8+j][n=lane&15],
//   D[m=(lane>>4)*4+r][n=lane&15].
// ---------------------------------------------------------------------------
extern "C" __global__ void __launch_bounds__(128)
lstm_k(const float* __restrict__ input, const float* __restrict__ w_ih,
       const float* __restrict__ w_hh, const float* __restrict__ b_ih,
       const float* __restrict__ b_hh, const float* __restrict__ in_proj_w,
       const float* __restrict__ in_proj_b,
       float* __restrict__ qo, float* __restrict__ ko, float* __restrict__ vo,
       float* __restrict__ ho)
{
  __shared__ __align__(16) _Float16 hbufh[2*16*40];  // [parity][n][k] 2560 B
  __shared__ __align__(16) float    xstf[8*390];     // x: [n][t][6pad] stride 390 dw
  const int tidb = threadIdx.x;
  const int wave = tidb >> 6;
  const int lane = tidb & 63;
  const int n    = lane & 15;        // batch col (0..7 valid, 8..15 pad)
  const int quad = lane >> 4;
  const int b0   = blockIdx.x * 8;

  // ---- build A-frags + bias C-init (once), activation scale folded in ----
  const int mrow = 16*wave + n;            // dim within gate for A rows
  const bool rv  = (mrow < NE);
  f16x8 ah[4], ax[4];
  f32x4 bi[4];
  #pragma unroll
  for (int G=0; G<4; ++G){
    const float sG = (G==2) ? (-2.f*L2E) : (-L2E);   // g gate: tanh via 2sig(2x)-1
    const int grow = rv ? (NE*G + mrow) : 0;
    #pragma unroll
    for (int j=0;j<8;++j){
      const int k = quad*8 + j;
      ah[G][j] = (rv && k < NE) ? (_Float16)(sG*w_hh[grow*NE + k]) : (_Float16)0;
      ax[G][j] = (rv && quad==0 && j < NIN) ? (_Float16)(sG*w_ih[grow*NIN + j]) : (_Float16)0;
    }
    #pragma unroll
    for (int r=0;r<4;++r){
      const int d = 16*wave + quad*4 + r;  // D row -> dim
      const int gr = (d < NE) ? (NE*G + d) : 0;
      bi[G][r] = (d < NE) ? sG*(b_ih[gr] + b_hh[gr]) : 0.f;
    }
  }
  // zero h double-buffer (1280 halves = 640 dwords)
  for (int i=tidb; i<640; i+=128) ((float*)hbufh)[i] = 0.f;

  float c0=0.f,c1=0.f,c2=0.f,c3=0.f;
  float h0f=0.f,h1f=0.f,h2f=0.f,h3f=0.f;
  const int hb = n*40 + quad*8;            // bh read offset (halves)
  const int hw = n*40 + 16*wave + 4*quad;  // h write offset (halves)
  const bool q0 = (quad == 0);
  const f16x8 zf8 = (f16x8)(_Float16)0;
  const float2* x2p = (const float2*)xstf;
  const int xb2 = (n&7)*195;               // pad lanes alias batch n-8 (finite, unused)

  for (int tc = 0; tc < Tlen; tc += 64) {
    // stage 64 steps x 8 batches x 5 inputs into padded [n][t][6] layout
    __syncthreads();   // protect xstf against stragglers of previous chunk
    for (int i = tidb; i < 2560; i += 128){
      const int nn = i/320, e = i%320;
      xstf[nn*390 + (e/5)*6 + (e%5)] =
        input[(size_t)(b0+nn)*(Tlen*NIN) + tc*5 + e];
    }
    __syncthreads();
    #pragma unroll 1
    for (int tl2 = 0; tl2 < 32; ++tl2) {
      // hoist x reads for BOTH half-steps (latency hides under par0 compute)
      const int base0 = xb2 + (2*tl2)*3;
      const float2 a0 = x2p[base0],   a1 = x2p[base0+1], a2 = x2p[base0+2];
      const float2 b1 = x2p[base0+3], b2 = x2p[base0+4], b3 = x2p[base0+5];
      #pragma unroll
      for (int par=0; par<2; ++par) {
        const _Float16* rbuf = hbufh + par*640;
        _Float16*       wbuf = hbufh + (par^1)*640;
        // B-frag (h-part) -- issue read early; ax-MFMAs don't depend on it
        const f16x8 bh = *(const f16x8*)(rbuf + hb);
        // B-frag (x-part): quad0 lanes carry [x0..x4,0,0,0]
        const float xv0 = par ? b1.x : a0.x;
        const float xv1 = par ? b1.y : a0.y;
        const float xv2 = par ? b2.x : a1.x;
        const float xv3 = par ? b2.y : a1.y;
        const float xv4 = par ? b3.x : a2.x;
        union { f16x8 v; h2v h[4]; } U;
        U.h[0].x=(_Float16)xv0; U.h[0].y=(_Float16)xv1;
        U.h[1].x=(_Float16)xv2; U.h[1].y=(_Float16)xv3;
        U.h[2].x=(_Float16)xv4; U.h[2].y=(_Float16)0;
        U.h[3]=(h2v)0;
        const f16x8 bx = q0 ? U.v : zf8;
        // 8 MFMAs: gates i,f,g,o (ax first; ah chained after bh arrives)
        f32x4 Ci = __builtin_amdgcn_mfma_f32_16x16x32_f16(ax[0], bx, bi[0], 0,0,0);
        f32x4 Cf = __builtin_amdgcn_mfma_f32_16x16x32_f16(ax[1], bx, bi[1], 0,0,0);
        f32x4 Cg = __builtin_amdgcn_mfma_f32_16x16x32_f16(ax[2], bx, bi[2], 0,0,0);
        f32x4 Co = __builtin_amdgcn_mfma_f32_16x16x32_f16(ax[3], bx, bi[3], 0,0,0);
        Ci = __builtin_amdgcn_mfma_f32_16x16x32_f16(ah[0], bh, Ci, 0,0,0);
        Cf = __builtin_amdgcn_mfma_f32_16x16x32_f16(ah[1], bh, Cf, 0,0,0);
        Cg = __builtin_amdgcn_mfma_f32_16x16x32_f16(ah[2], bh, Cg, 0,0,0);
        Co = __builtin_amdgcn_mfma_f32_16x16x32_f16(ah[3], bh, Co, 0,0,0);
        // activations: preacts arrive pre-scaled: sig = rcp(1+exp2(C));
        // g gate: tanh = 2*rcp(1+exp2(C)) - 1 (C already -2L2E*a)
        {
          const float iv = frcp(1.f + fexp2(Ci[0]));
          const float fv = frcp(1.f + fexp2(Cf[0]));
          const float gv = fmaf(2.f, frcp(1.f + fexp2(Cg[0])), -1.f);
          const float ov = frcp(1.f + fexp2(Co[0]));
          c0 = fmaf(fv, c0, iv*gv);
          const float r2 = frcp(1.f + fexp2((2.f*L2E)*c0));
          h0f = ov * fmaf(-2.f, r2, 1.f);
        }
        {
          const float iv = frcp(1.f + fexp2(Ci[1]));
          const float fv = frcp(1.f + fexp2(Cf[1]));
          const float gv = fmaf(2.f, frcp(1.f + fexp2(Cg[1])), -1.f);
          const float ov = frcp(1.f + fexp2(Co[1]));
          c1 = fmaf(fv, c1, iv*gv);
          const float r2 = frcp(1.f + fexp2((2.f*L2E)*c1));
          h1f = ov * fmaf(-2.f, r2, 1.f);
        }
        {
          const float iv = frcp(1.f + fexp2(Ci[2]));
          const float fv = frcp(1.f + fexp2(Cf[2]));
          const float gv = fmaf(2.f, frcp(1.f + fexp2(Cg[2])), -1.f);
          const float ov = frcp(1.f + fexp2(Co[2]));
          c2 = fmaf(fv, c2, iv*gv);
          const float r2 = frcp(1.f + fexp2((2.f*L2E)*c2));
          h2f = ov * fmaf(-2.f, r2, 1.f);
        }
        {
          const float iv = frcp(1.f + fexp2(Ci[3]));
          const float fv = frcp(1.f + fexp2(Cf[3]));
          const float gv = fmaf(2.f, frcp(1.f + fexp2(Cg[3])), -1.f);
          const float ov = frcp(1.f + fexp2(Co[3]));
          c3 = fmaf(fv, c3, iv*gv);
          const float r2 = frcp(1.f + fexp2((2.f*L2E)*c3));
          h3f = ov * fmaf(-2.f, r2, 1.f);
        }
        // pack h -> fp16, write 4 contiguous dims (8B)
        h2v q01, q23;
        q01.x=(_Float16)h0f; q01.y=(_Float16)h1f;
        q23.x=(_Float16)h2f; q23.y=(_Float16)h3f;
        float2 wv;
        wv.x = __builtin_bit_cast(float, q01);
        wv.y = __builtin_bit_cast(float, q23);
        *(float2*)(wbuf + hw) = wv;
        __syncthreads();
      }
    }
  }

  // ---- tail: stash fp32 h,c; project q(h), k(c), v(c) ----
  float* hf = xstf;            // [8][36]
  float* cf = xstf + 8*36;
  __syncthreads();
  if (n < 8) {
    const int d0 = 16*wave + 4*quad;
    float4 hv4; hv4.x=h0f; hv4.y=h1f; hv4.z=h2f; hv4.w=h3f;
    float4 cv4; cv4.x=c0;  cv4.y=c1;  cv4.z=c2;  cv4.w=c3;
    *(float4*)(&hf[n*36 + d0]) = hv4;
    *(float4*)(&cf[n*36 + d0]) = cv4;
  }
  __syncthreads();
  for (int i = tidb; i < 8*NE; i += 128){
    const int nn = i/NE, d = i%NE;
    ho[(size_t)(b0+nn)*NE + d] = hf[nn*36 + d];
  }
  const float QS = 0.31622776601683794f;     // 1/sqrt(10)
  for (int i = tidb; i < 90*8; i += 128){
    const int o  = i % 90;
    const int nn = i / 90;
    const float* wrow = in_proj_w + o*NE;
    const float* src  = (o < NE) ? &hf[nn*36] : &cf[nn*36];
    float acc = in_proj_b[o];
    #pragma unroll
    for (int k2=0;k2<NE;k2++) acc = fmaf(wrow[k2], src[k2], acc);
    const int b = b0 + nn;
    if (o < 30)      { qo[(o/10)*B10 + b*10 + (o%10)] = acc * QS; }
    else if (o < 60) { const int u=o-30; ko[(u/10)*B10 + b*10 + (u%10)] = acc; }
    else             { const int u=o-60; vo[(u/10)*B10 + b*10 + (u%10)] = acc; }
  }
}

// ---------------------------------------------------------------------------
// Kernel 2 (R9 load-batching): flash attention partials. 1 thread = 1 query.
// R8 implied attn_part ~150us vs ~10us issue-math -> theory: interleaved
// load/use + unroll-1 serialized ~10 dependent L2 waits per chunk. Fix:
// 4-key chunks with K AND V loaded into named locals BEFORE any use (one
// vmcnt window per chunk); __launch_bounds__(256,2) guarantees the ~115-reg
// live set never spills (R4 lesson: spills here cost GBs of scratch).
// NS up to 32 ksplits -> up to 6144 waves for latency hiding.
// ---------------------------------------------------------------------------
extern "C" __global__ void __launch_bounds__(256, 2)
attn_part(const float* __restrict__ q, const float* __restrict__ k,
          const float* __restrict__ v, float* __restrict__ part, int nkeys)
{
  const int t    = threadIdx.x;
  const int qr   = blockIdx.x*256 + t;
  const int head = blockIdx.y;
  const int ks   = blockIdx.z;
  const float* kh = k + (size_t)head*B10;
  const float* vh = v + (size_t)head*B10;
  float qreg[10];
  {
    const float2* qp = (const float2*)(q + (size_t)head*B10 + (size_t)qr*10);
    #pragma unroll
    for (int i=0;i<5;i++){ float2 t2=qp[i]; qreg[2*i]=t2.x; qreg[2*i+1]=t2.y; }
  }
  float m = -INFINITY, l = 0.f, acc[10];
  #pragma unroll
  for (int d=0;d<10;d++) acc[d]=0.f;

  const int k0 = ks * nkeys;
  #pragma unroll 1
  for (int cch=0; cch<nkeys; cch+=4) {
    const float4* kp4 = (const float4*)(kh + (size_t)(k0+cch)*10);
    const float4* vp4 = (const float4*)(vh + (size_t)(k0+cch)*10);
    float4 kr[10], vr[10];
    #pragma unroll
    for (int i=0;i<10;i++) kr[i] = kp4[i];
    #pragma unroll
    for (int i=0;i<10;i++) vr[i] = vp4[i];
    const float* kf = (const float*)kr;   // 4 rows x 10 floats
    const float* vf = (const float*)vr;
    float s[4];
    #pragma unroll
    for (int u=0;u<4;u++){
      float sv = 0.f;
      #pragma unroll
      for (int i=0;i<10;i++) sv = fmaf(qreg[i], kf[u*10+i], sv);
      s[u]=sv;
    }
    const float mc01 = fmaxf(s[0], s[1]);
    const float mc23 = fmaxf(s[2], s[3]);
    const float mnew = fmaxf(m, fmaxf(mc01, mc23));
    const float corr = fexp2(L2E*(m - mnew));   // m=-inf first chunk -> 0
    l *= corr;
    #pragma unroll
    for (int d=0;d<10;d++) acc[d]*=corr;
    #pragma unroll
    for (int u=0;u<4;u++){
      const float p = fexp2(L2E*(s[u]-mnew));
      l += p;
      #pragma unroll
      for (int d=0;d<10;d++) acc[d] = fmaf(p, vf[u*10+d], acc[d]);
    }
    m = mnew;
  }
  float* pp = part + ((size_t)(head*Bsz + qr)*gridDim.z + ks)*12;
  pp[0]=m; pp[1]=l;
  #pragma unroll
  for (int d=0;d<10;d++) pp[2+d]=acc[d];
}

// ---------------------------------------------------------------------------
// Kernel 3: fused merge + out_proj + residual + LN + MLP + LN + head.
// One wave per row. Lane d<30 online-merges its (head, dim) ctx component
// from the NS partials inline. (unchanged R8)
// ---------------------------------------------------------------------------
extern "C" __global__ void __launch_bounds__(256)
tail_k(const float* __restrict__ part, int ns, const float* __restrict__ hn,
       const float* __restrict__ out_proj_w, const float* __restrict__ out_proj_b,
       const float* __restrict__ fc1_w, const float* __restrict__ fc1_b,
       const float* __restrict__ fc2_w, const float* __restrict__ fc2_b,
       const float* __restrict__ ln_g, const float* __restrict__ ln_b,
       const float* __restrict__ out_w, const float* __restrict__ out_b,
       float* __restrict__ out)
{
  __shared__ __align__(16) float buf[4][32];
  const int wave = threadIdx.x >> 6;
  const int lane = threadIdx.x & 63;
  const int b = blockIdx.x*4 + wave;
  const bool act = (lane < NE);
  if (lane < 32) buf[wave][lane] = 0.f;
  __builtin_amdgcn_wave_barrier();
  if (act) {
    const int head = lane/10, dd = lane%10;
    const float* p = part + ((size_t)(head*Bsz + b)*ns)*12;
    float M = -INFINITY, L = 0.f, O = 0.f;
    for (int i=0;i<ns;i++){
      const float mi = p[i*12], li = p[i*12+1], ai = p[i*12+2+dd];
      const float Mn = fmaxf(M, mi);
      const float cw = fexp2(L2E*(M - Mn));
      const float wi = fexp2(L2E*(mi - Mn));
      L = fmaf(li, wi, L*cw);
      O = fmaf(ai, wi, O*cw);
      M = Mn;
    }
    buf[wave][lane] = O / L;
  }
  __builtin_amdgcn_wave_barrier();
  float arr[32];
  loadarr32(arr, &buf[wave][0]);
  const float hv = act ? hn[b*NE+lane] : 0.f;
  float x = 0.f;
  if (act) {
    float a = out_proj_b[lane];
    #pragma unroll
    for (int k2=0;k2<NE;k2++) a = fmaf(out_proj_w[lane*NE+k2], arr[k2], a);
    x = a + hv;                       // attn_out + h_n
  }
  // LN1
  __builtin_amdgcn_wave_barrier();
  if (act) buf[wave][lane] = x;
  __builtin_amdgcn_wave_barrier();
  loadarr32(arr, &buf[wave][0]);
  float s1=0.f, s2=0.f;
  #pragma unroll
  for (int k2=0;k2<32;k2++){ s1+=arr[k2]; s2=fmaf(arr[k2],arr[k2],s2); }
  float mu = s1*(1.f/30.f);
  float var = s2*(1.f/30.f) - mu*mu;
  float rs = rsqrtf(var + 1e-5f);
  float x1 = 0.f;
  if (act) x1 = fmaf((x-mu)*rs, ln_g[lane], ln_b[lane]);
  // fc1 + exact GELU
  __builtin_amdgcn_wave_barrier();
  if (act) buf[wave][lane] = x1;
  __builtin_amdgcn_wave_barrier();
  loadarr32(arr, &buf[wave][0]);
  float gv = 0.f;
  if (act) {
    float a = fc1_b[lane];
    #pragma unroll
    for (int k2=0;k2<NE;k2++) a = fmaf(fc1_w[lane*NE+k2], arr[k2], a);
    gv = 0.5f*a*(1.f + erff(a*0.70710678118654752f));
  }
  // fc2
  __builtin_amdgcn_wave_barrier();
  if (act) buf[wave][lane] = gv;
  __builtin_amdgcn_wave_barrier();
  loadarr32(arr, &buf[wave][0]);
  float y = 0.f;
  if (act) {
    float a = fc2_b[lane];
    #pragma unroll
    for (int k2=0;k2<NE;k2++) a = fmaf(fc2_w[lane*NE+k2], arr[k2], a);
    y = x1 + a;                        // residual x1 + fc
  }
  // LN2
  __builtin_amdgcn_wave_barrier();
  if (act) buf[wave][lane] = y;
  __builtin_amdgcn_wave_barrier();
  loadarr32(arr, &buf[wave][0]);
  s1=0.f; s2=0.f;
  #pragma unroll
  for (int k2=0;k2<32;k2++){ s1+=arr[k2]; s2=fmaf(arr[k2],arr[k2],s2); }
  mu = s1*(1.f/30.f);
  var = s2*(1.f/30.f) - mu*mu;
  rs = rsqrtf(var + 1e-5f);
  float x2 = 0.f;
  if (act) x2 = fmaf((y-mu)*rs, ln_g[lane], ln_b[lane]);
  // head: [3,30]
  __builtin_amdgcn_wave_barrier();
  if (act) buf[wave][lane] = x2;
  __builtin_amdgcn_wave_barrier();
  loadarr32(arr, &buf[wave][0]);
  if (lane < 3) {
    float a = out_b[lane];
    #pragma unroll
    for (int k2=0;k2<NE;k2++) a = fmaf(out_w[lane*NE+k2], arr[k2], a);
    out[b*3 + lane] = a;
  }
}

extern "C" void kernel_launch(void* const* d_in, const int* in_sizes, int n_in,
                              void* d_out, int out_size, void* d_ws, size_t ws_size,
                              hipStream_t stream)
{
  const float* input      = (const float*)d_in[0];
  const float* w_ih       = (const float*)d_in[1];
  const float* w_hh       = (const float*)d_in[2];
  const float* b_ih       = (const float*)d_in[3];
  const float* b_hh       = (const float*)d_in[4];
  const float* in_proj_w  = (const float*)d_in[5];
  const float* in_proj_b  = (const float*)d_in[6];
  const float* out_proj_w = (const float*)d_in[7];
  const float* out_proj_b = (const float*)d_in[8];
  const float* fc1_w      = (const float*)d_in[9];
  const float* fc1_b      = (const float*)d_in[10];
  const float* fc2_w      = (const float*)d_in[11];
  const float* fc2_b      = (const float*)d_in[12];
  const float* ln_g       = (const float*)d_in[13];
  const float* ln_b       = (const float*)d_in[14];
  const float* out_w      = (const float*)d_in[15];
  const float* out_b      = (const float*)d_in[16];

  float* ws = (float*)d_ws;
  float* qo   = ws;                 // [3][4096][10]
  float* ko   = ws + 122880;        // [3][4096][10]
  float* vo   = ws + 245760;        // [3][4096][10]
  float* hn   = ws + 368640;        // [4096][30]
  float* part = ws + 491520;        // [3][4096][NS][12]

  // NS cascade by ws capacity (deterministic: ws_size fixed -> graph-safe)
  const size_t need32 = ((size_t)491520 + (size_t)3*4096*32*12) * 4;
  const size_t need16 = ((size_t)491520 + (size_t)3*4096*16*12) * 4;
  const int NS = (ws_size >= need32) ? 32 : (ws_size >= need16) ? 16 : 8;

  lstm_k<<<Bsz/8, 128, 0, stream>>>(input, w_ih, w_hh, b_ih, b_hh,
                                    in_proj_w, in_proj_b, qo, ko, vo, hn);
  attn_part<<<dim3(Bsz/256, 3, NS), 256, 0, stream>>>(qo, ko, vo, part, Bsz/NS);
  tail_k<<<Bsz/4, 256, 0, stream>>>(part, NS, hn, out_proj_w, out_proj_b,
                                    fc1_w, fc1_b, fc2_w, fc2_b,
                                    ln_g, ln_b, out_w, out_b, (float*)d_out);
}

// Round 10
// 404.177 us; speedup vs baseline: 1.2782x; 1.2782x over previous
//
#include <hip/hip_runtime.h>
#include <math.h>

// Problem constants
#define Bsz  4096
#define Tlen 512
#define NE   30
#define NIN  5
#define HD10 10
#define B10  (Bsz*HD10)   // per-head plane: 40960 floats

typedef _Float16 h2v  __attribute__((ext_vector_type(2)));
typedef _Float16 f16x8 __attribute__((ext_vector_type(8)));
typedef float    f32x4 __attribute__((ext_vector_type(4)));

__device__ __forceinline__ float fexp2(float x){ return __builtin_amdgcn_exp2f(x); }
__device__ __forceinline__ float frcp (float x){ return __builtin_amdgcn_rcpf(x); }
#define L2E 1.4426950408889634f

__device__ __forceinline__ void loadarr32(float arr[32], const float* bufrow){
  const float4* p4 = (const float4*)bufrow;
  #pragma unroll
  for (int q4=0;q4<8;q4++){ float4 vv=p4[q4]; arr[4*q4]=vv.x; arr[4*q4+1]=vv.y; arr[4*q4+2]=vv.z; arr[4*q4+3]=vv.w; }
}

// ---------------------------------------------------------------------------
// Kernel 1 (MFMA LSTM) -- exact R8 revert (267us best-known).
// One block (128 thr, 2 waves) per 16-batch group; grid 256.
// R9 lesson: halving batches/block doubles total work; interleaving gain
// (+35% VALUBusy) can't pay for 2x duplication. Grid pinned 256x16.
// Fragment layouts (m89/m120-verified):
//   A[m=lane&15][k=(lane>>4)*8+j], B[k=(lane>>4)*8+j][n=lane&15],
//   D[m=(lane>>4)*4+r][n=lane&15].
// ---------------------------------------------------------------------------
extern "C" __global__ void __launch_bounds__(128)
lstm_k(const float* __restrict__ input, const float* __restrict__ w_ih,
       const float* __restrict__ w_hh, const float* __restrict__ b_ih,
       const float* __restrict__ b_hh, const float* __restrict__ in_proj_w,
       const float* __restrict__ in_proj_b,
       float* __restrict__ qo, float* __restrict__ ko, float* __restrict__ vo,
       float* __restrict__ ho)
{
  __shared__ __align__(16) _Float16 hbufh[2*16*40];  // [parity][n][k] 2560 B
  __shared__ __align__(16) float    xstf[16*390];    // x: [n][t][6pad] stride 390 dw
  const int tidb = threadIdx.x;
  const int wave = tidb >> 6;
  const int lane = tidb & 63;
  const int n    = lane & 15;        // batch within group (B-frag/D col)
  const int quad = lane >> 4;
  const int b0   = blockIdx.x * 16;

  // ---- build A-frags + bias C-init (once), activation scale folded in ----
  const int mrow = 16*wave + n;            // dim within gate for A rows
  const bool rv  = (mrow < NE);
  f16x8 ah[4], ax[4];
  f32x4 bi[4];
  #pragma unroll
  for (int G=0; G<4; ++G){
    const float sG = (G==2) ? (-2.f*L2E) : (-L2E);   // g gate: tanh via 2sig(2x)-1
    const int grow = rv ? (NE*G + mrow) : 0;
    #pragma unroll
    for (int j=0;j<8;++j){
      const int k = quad*8 + j;
      ah[G][j] = (rv && k < NE) ? (_Float16)(sG*w_hh[grow*NE + k]) : (_Float16)0;
      ax[G][j] = (rv && quad==0 && j < NIN) ? (_Float16)(sG*w_ih[grow*NIN + j]) : (_Float16)0;
    }
    #pragma unroll
    for (int r=0;r<4;++r){
      const int d = 16*wave + quad*4 + r;  // D row -> dim
      const int gr = (d < NE) ? (NE*G + d) : 0;
      bi[G][r] = (d < NE) ? sG*(b_ih[gr] + b_hh[gr]) : 0.f;
    }
  }
  // zero h double-buffer
  for (int i=tidb; i<640; i+=128) ((float*)hbufh)[i] = 0.f;

  float c0=0.f,c1=0.f,c2=0.f,c3=0.f;
  float h0f=0.f,h1f=0.f,h2f=0.f,h3f=0.f;
  const int hb = n*40 + quad*8;            // bh read offset (halves)
  const int hw = n*40 + 16*wave + 4*quad;  // h write offset (halves)
  const bool q0 = (quad == 0);
  const f16x8 zf8 = (f16x8)(_Float16)0;
  const float2* x2p = (const float2*)xstf;
  const int xb2 = n*195;                   // float2 index base for this batch

  for (int tc = 0; tc < Tlen; tc += 64) {
    // stage 64 steps x 16 batches x 5 inputs into padded [n][t][6] layout
    __syncthreads();   // protect xstf against stragglers of previous chunk
    for (int i = tidb; i < 5120; i += 128){
      const int nn = i/320, e = i%320;
      xstf[nn*390 + (e/5)*6 + (e%5)] =
        input[(size_t)(b0+nn)*(Tlen*NIN) + tc*5 + e];
    }
    __syncthreads();
    #pragma unroll 1
    for (int tl2 = 0; tl2 < 32; ++tl2) {
      // hoist x reads for BOTH half-steps (latency hides under par0 compute)
      const int base0 = xb2 + (2*tl2)*3;
      const float2 a0 = x2p[base0],   a1 = x2p[base0+1], a2 = x2p[base0+2];
      const float2 b1 = x2p[base0+3], b2 = x2p[base0+4], b3 = x2p[base0+5];
      #pragma unroll
      for (int par=0; par<2; ++par) {
        const _Float16* rbuf = hbufh + par*640;
        _Float16*       wbuf = hbufh + (par^1)*640;
        // B-frag (h-part) -- issue read early; ax-MFMAs don't depend on it
        const f16x8 bh = *(const f16x8*)(rbuf + hb);
        // B-frag (x-part): quad0 lanes carry [x0..x4,0,0,0]
        const float xv0 = par ? b1.x : a0.x;
        const float xv1 = par ? b1.y : a0.y;
        const float xv2 = par ? b2.x : a1.x;
        const float xv3 = par ? b2.y : a1.y;
        const float xv4 = par ? b3.x : a2.x;
        union { f16x8 v; h2v h[4]; } U;
        U.h[0].x=(_Float16)xv0; U.h[0].y=(_Float16)xv1;
        U.h[1].x=(_Float16)xv2; U.h[1].y=(_Float16)xv3;
        U.h[2].x=(_Float16)xv4; U.h[2].y=(_Float16)0;
        U.h[3]=(h2v)0;
        const f16x8 bx = q0 ? U.v : zf8;
        // 8 MFMAs: gates i,f,g,o (ax first; ah chained after bh arrives)
        f32x4 Ci = __builtin_amdgcn_mfma_f32_16x16x32_f16(ax[0], bx, bi[0], 0,0,0);
        f32x4 Cf = __builtin_amdgcn_mfma_f32_16x16x32_f16(ax[1], bx, bi[1], 0,0,0);
        f32x4 Cg = __builtin_amdgcn_mfma_f32_16x16x32_f16(ax[2], bx, bi[2], 0,0,0);
        f32x4 Co = __builtin_amdgcn_mfma_f32_16x16x32_f16(ax[3], bx, bi[3], 0,0,0);
        Ci = __builtin_amdgcn_mfma_f32_16x16x32_f16(ah[0], bh, Ci, 0,0,0);
        Cf = __builtin_amdgcn_mfma_f32_16x16x32_f16(ah[1], bh, Cf, 0,0,0);
        Cg = __builtin_amdgcn_mfma_f32_16x16x32_f16(ah[2], bh, Cg, 0,0,0);
        Co = __builtin_amdgcn_mfma_f32_16x16x32_f16(ah[3], bh, Co, 0,0,0);
        // activations: preacts arrive pre-scaled: sig = rcp(1+exp2(C));
        // g gate: tanh = 2*rcp(1+exp2(C)) - 1 (C already -2L2E*a)
        {
          const float iv = frcp(1.f + fexp2(Ci[0]));
          const float fv = frcp(1.f + fexp2(Cf[0]));
          const float gv = fmaf(2.f, frcp(1.f + fexp2(Cg[0])), -1.f);
          const float ov = frcp(1.f + fexp2(Co[0]));
          c0 = fmaf(fv, c0, iv*gv);
          const float r2 = frcp(1.f + fexp2((2.f*L2E)*c0));
          h0f = ov * fmaf(-2.f, r2, 1.f);
        }
        {
          const float iv = frcp(1.f + fexp2(Ci[1]));
          const float fv = frcp(1.f + fexp2(Cf[1]));
          const float gv = fmaf(2.f, frcp(1.f + fexp2(Cg[1])), -1.f);
          const float ov = frcp(1.f + fexp2(Co[1]));
          c1 = fmaf(fv, c1, iv*gv);
          const float r2 = frcp(1.f + fexp2((2.f*L2E)*c1));
          h1f = ov * fmaf(-2.f, r2, 1.f);
        }
        {
          const float iv = frcp(1.f + fexp2(Ci[2]));
          const float fv = frcp(1.f + fexp2(Cf[2]));
          const float gv = fmaf(2.f, frcp(1.f + fexp2(Cg[2])), -1.f);
          const float ov = frcp(1.f + fexp2(Co[2]));
          c2 = fmaf(fv, c2, iv*gv);
          const float r2 = frcp(1.f + fexp2((2.f*L2E)*c2));
          h2f = ov * fmaf(-2.f, r2, 1.f);
        }
        {
          const float iv = frcp(1.f + fexp2(Ci[3]));
          const float fv = frcp(1.f + fexp2(Cf[3]));
          const float gv = fmaf(2.f, frcp(1.f + fexp2(Cg[3])), -1.f);
          const float ov = frcp(1.f + fexp2(Co[3]));
          c3 = fmaf(fv, c3, iv*gv);
          const float r2 = frcp(1.f + fexp2((2.f*L2E)*c3));
          h3f = ov * fmaf(-2.f, r2, 1.f);
        }
        // pack h -> fp16, write 4 contiguous dims (8B)
        h2v q01, q23;
        q01.x=(_Float16)h0f; q01.y=(_Float16)h1f;
        q23.x=(_Float16)h2f; q23.y=(_Float16)h3f;
        float2 wv;
        wv.x = __builtin_bit_cast(float, q01);
        wv.y = __builtin_bit_cast(float, q23);
        *(float2*)(wbuf + hw) = wv;
        __syncthreads();
      }
    }
  }

  // ---- tail: stash fp32 h,c; project q(h), k(c), v(c) ----
  float* hf = xstf;            // [16][36]
  float* cf = xstf + 16*36;
  __syncthreads();
  {
    const int d0 = 16*wave + 4*quad;
    float4 hv4; hv4.x=h0f; hv4.y=h1f; hv4.z=h2f; hv4.w=h3f;
    float4 cv4; cv4.x=c0;  cv4.y=c1;  cv4.z=c2;  cv4.w=c3;
    *(float4*)(&hf[n*36 + d0]) = hv4;
    *(float4*)(&cf[n*36 + d0]) = cv4;
  }
  __syncthreads();
  for (int i = tidb; i < 16*NE; i += 128){
    const int nn = i/NE, d = i%NE;
    ho[(size_t)(b0+nn)*NE + d] = hf[nn*36 + d];
  }
  const float QS = 0.31622776601683794f;     // 1/sqrt(10)
  for (int i = tidb; i < 90*16; i += 128){
    const int o  = i % 90;
    const int nn = i / 90;
    const float* wrow = in_proj_w + o*NE;
    const float* src  = (o < NE) ? &hf[nn*36] : &cf[nn*36];
    float acc = in_proj_b[o];
    #pragma unroll
    for (int k2=0;k2<NE;k2++) acc = fmaf(wrow[k2], src[k2], acc);
    const int b = b0 + nn;
    if (o < 30)      { qo[(o/10)*B10 + b*10 + (o%10)] = acc * QS; }
    else if (o < 60) { const int u=o-30; ko[(u/10)*B10 + b*10 + (u%10)] = acc; }
    else             { const int u=o-60; vo[(u/10)*B10 + b*10 + (u%10)] = acc; }
  }
}

// ---------------------------------------------------------------------------
// Kernel 2 (R10: cooperative LDS staging): flash attention partials.
// Thread = query. grid (16 qblocks, 3 heads, NS), block 256.
// 64-key K/V tiles staged cooperatively (coalesced float4, ONE vmcnt window
// + 2 barriers per tile) -> removes the per-thread serial global K/V stream
// that every R5-R9 variant kept (suspect for the stubborn ~150us gap).
// Compute reads LDS broadcasts (all lanes read same key row: conflict-free).
// Live set ~45 VGPRs -> no spill at any occupancy target.
// ---------------------------------------------------------------------------
extern "C" __global__ void __launch_bounds__(256)
attn_part(const float* __restrict__ q, const float* __restrict__ k,
          const float* __restrict__ v, float* __restrict__ part, int nkeys)
{
  __shared__ __align__(16) float kst[640];   // 64 keys x 10
  __shared__ __align__(16) float vst[640];
  const int t    = threadIdx.x;
  const int qr   = blockIdx.x*256 + t;
  const int head = blockIdx.y;
  const int ks   = blockIdx.z;
  const float* kh = k + (size_t)head*B10;
  const float* vh = v + (size_t)head*B10;
  float qreg[10];
  {
    const float2* qp = (const float2*)(q + (size_t)head*B10 + (size_t)qr*10);
    #pragma unroll
    for (int i=0;i<5;i++){ float2 t2=qp[i]; qreg[2*i]=t2.x; qreg[2*i+1]=t2.y; }
  }
  float m = -INFINITY, l = 0.f, acc[10];
  #pragma unroll
  for (int d=0;d<10;d++) acc[d]=0.f;

  const int k0 = ks * nkeys;
  const int nt = nkeys >> 6;           // 64-key tiles
  #pragma unroll 1
  for (int ti=0; ti<nt; ++ti){
    const int kt0 = k0 + (ti<<6);
    __syncthreads();                   // previous tile's reads complete
    {
      const float4* ksrc = (const float4*)(kh + (size_t)kt0*10);
      const float4* vsrc = (const float4*)(vh + (size_t)kt0*10);
      for (int i=t; i<320; i+=256){
        if (i < 160) ((float4*)kst)[i]     = ksrc[i];
        else         ((float4*)vst)[i-160] = vsrc[i-160];
      }
    }
    __syncthreads();                   // staging visible
    #pragma unroll 1
    for (int c8=0; c8<64; c8+=8){
      float s[8];
      #pragma unroll
      for (int u=0;u<8;u++){
        const float2* kp = (const float2*)(kst + (c8+u)*10);
        float sv = 0.f;
        #pragma unroll
        for (int i=0;i<5;i++){ float2 kk=kp[i]; sv=fmaf(qreg[2*i],kk.x,sv); sv=fmaf(qreg[2*i+1],kk.y,sv); }
        s[u]=sv;
      }
      float mc = s[0];
      #pragma unroll
      for (int u=1;u<8;u++) mc = fmaxf(mc, s[u]);
      const float mnew = fmaxf(m, mc);
      const float corr = fexp2(L2E*(m - mnew));   // m=-inf first chunk -> 0
      l *= corr;
      #pragma unroll
      for (int d=0;d<10;d++) acc[d]*=corr;
      #pragma unroll
      for (int u=0;u<8;u++){
        const float p = fexp2(L2E*(s[u]-mnew));
        l += p;
        const float2* vp = (const float2*)(vst + (c8+u)*10);
        #pragma unroll
        for (int i=0;i<5;i++){ float2 vv=vp[i]; acc[2*i]=fmaf(p,vv.x,acc[2*i]); acc[2*i+1]=fmaf(p,vv.y,acc[2*i+1]); }
      }
      m = mnew;
    }
  }
  float* pp = part + ((size_t)(head*Bsz + qr)*gridDim.z + ks)*12;
  pp[0]=m; pp[1]=l;
  #pragma unroll
  for (int d=0;d<10;d++) pp[2+d]=acc[d];
}

// ---------------------------------------------------------------------------
// Kernel 3 (R10: LDS weights): fused merge + out_proj + LN + MLP + LN + head.
// One wave per row. Weight matrices staged to LDS once per block (coalesced)
// -- replaces 150 lane-strided global gathers per wave (57 cache lines per
// load instr, the other suspect for the gap). Stride-30 LDS reads = 2-way
// bank alias = free (m136).
// ---------------------------------------------------------------------------
extern "C" __global__ void __launch_bounds__(256)
tail_k(const float* __restrict__ part, int ns, const float* __restrict__ hn,
       const float* __restrict__ out_proj_w, const float* __restrict__ out_proj_b,
       const float* __restrict__ fc1_w, const float* __restrict__ fc1_b,
       const float* __restrict__ fc2_w, const float* __restrict__ fc2_b,
       const float* __restrict__ ln_g, const float* __restrict__ ln_b,
       const float* __restrict__ out_w, const float* __restrict__ out_b,
       float* __restrict__ out)
{
  __shared__ __align__(16) float buf[4][32];
  __shared__ float wl[2880];   // [0]=out_proj_w 900, [900]=fc1_w, [1800]=fc2_w, [2700]=out_w 90
  const int tidb = threadIdx.x;
  for (int i=tidb;i<900;i+=256) wl[i]       = out_proj_w[i];
  for (int i=tidb;i<900;i+=256) wl[900+i]   = fc1_w[i];
  for (int i=tidb;i<900;i+=256) wl[1800+i]  = fc2_w[i];
  if (tidb < 90) wl[2700+tidb] = out_w[tidb];
  const int wave = tidb >> 6;
  const int lane = tidb & 63;
  const int b = blockIdx.x*4 + wave;
  const bool act = (lane < NE);
  if (lane < 32) buf[wave][lane] = 0.f;
  __syncthreads();
  if (act) {
    const int head = lane/10, dd = lane%10;
    const float* p = part + ((size_t)(head*Bsz + b)*ns)*12;
    float M = -INFINITY, L = 0.f, O = 0.f;
    for (int i=0;i<ns;i++){
      const float mi = p[i*12], li = p[i*12+1], ai = p[i*12+2+dd];
      const float Mn = fmaxf(M, mi);
      const float cw = fexp2(L2E*(M - Mn));
      const float wi = fexp2(L2E*(mi - Mn));
      L = fmaf(li, wi, L*cw);
      O = fmaf(ai, wi, O*cw);
      M = Mn;
    }
    buf[wave][lane] = O / L;
  }
  __builtin_amdgcn_wave_barrier();
  float arr[32];
  loadarr32(arr, &buf[wave][0]);
  const float hv = act ? hn[b*NE+lane] : 0.f;
  float x = 0.f;
  if (act) {
    float a = out_proj_b[lane];
    #pragma unroll
    for (int k2=0;k2<NE;k2++) a = fmaf(wl[lane*NE+k2], arr[k2], a);
    x = a + hv;                       // attn_out + h_n
  }
  // LN1
  __builtin_amdgcn_wave_barrier();
  if (act) buf[wave][lane] = x;
  __builtin_amdgcn_wave_barrier();
  loadarr32(arr, &buf[wave][0]);
  float s1=0.f, s2=0.f;
  #pragma unroll
  for (int k2=0;k2<32;k2++){ s1+=arr[k2]; s2=fmaf(arr[k2],arr[k2],s2); }
  float mu = s1*(1.f/30.f);
  float var = s2*(1.f/30.f) - mu*mu;
  float rs = rsqrtf(var + 1e-5f);
  float x1 = 0.f;
  if (act) x1 = fmaf((x-mu)*rs, ln_g[lane], ln_b[lane]);
  // fc1 + exact GELU
  __builtin_amdgcn_wave_barrier();
  if (act) buf[wave][lane] = x1;
  __builtin_amdgcn_wave_barrier();
  loadarr32(arr, &buf[wave][0]);
  float gv = 0.f;
  if (act) {
    float a = fc1_b[lane];
    #pragma unroll
    for (int k2=0;k2<NE;k2++) a = fmaf(wl[900+lane*NE+k2], arr[k2], a);
    gv = 0.5f*a*(1.f + erff(a*0.70710678118654752f));
  }
  // fc2
  __builtin_amdgcn_wave_barrier();
  if (act) buf[wave][lane] = gv;
  __builtin_amdgcn_wave_barrier();
  loadarr32(arr, &buf[wave][0]);
  float y = 0.f;
  if (act) {
    float a = fc2_b[lane];
    #pragma unroll
    for (int k2=0;k2<NE;k2++) a = fmaf(wl[1800+lane*NE+k2], arr[k2], a);
    y = x1 + a;                        // residual x1 + fc
  }
  // LN2
  __builtin_amdgcn_wave_barrier();
  if (act) buf[wave][lane] = y;
  __builtin_amdgcn_wave_barrier();
  loadarr32(arr, &buf[wave][0]);
  s1=0.f; s2=0.f;
  #pragma unroll
  for (int k2=0;k2<32;k2++){ s1+=arr[k2]; s2=fmaf(arr[k2],arr[k2],s2); }
  mu = s1*(1.f/30.f);
  var = s2*(1.f/30.f) - mu*mu;
  rs = rsqrtf(var + 1e-5f);
  float x2 = 0.f;
  if (act) x2 = fmaf((y-mu)*rs, ln_g[lane], ln_b[lane]);
  // head: [3,30]
  __builtin_amdgcn_wave_barrier();
  if (act) buf[wave][lane] = x2;
  __builtin_amdgcn_wave_barrier();
  loadarr32(arr, &buf[wave][0]);
  if (lane < 3) {
    float a = out_b[lane];
    #pragma unroll
    for (int k2=0;k2<NE;k2++) a = fmaf(wl[2700+lane*NE+k2], arr[k2], a);
    out[b*3 + lane] = a;
  }
}

extern "C" void kernel_launch(void* const* d_in, const int* in_sizes, int n_in,
                              void* d_out, int out_size, void* d_ws, size_t ws_size,
                              hipStream_t stream)
{
  const float* input      = (const float*)d_in[0];
  const float* w_ih       = (const float*)d_in[1];
  const float* w_hh       = (const float*)d_in[2];
  const float* b_ih       = (const float*)d_in[3];
  const float* b_hh       = (const float*)d_in[4];
  const float* in_proj_w  = (const float*)d_in[5];
  const float* in_proj_b  = (const float*)d_in[6];
  const float* out_proj_w = (const float*)d_in[7];
  const float* out_proj_b = (const float*)d_in[8];
  const float* fc1_w      = (const float*)d_in[9];
  const float* fc1_b      = (const float*)d_in[10];
  const float* fc2_w      = (const float*)d_in[11];
  const float* fc2_b      = (const float*)d_in[12];
  const float* ln_g       = (const float*)d_in[13];
  const float* ln_b       = (const float*)d_in[14];
  const float* out_w      = (const float*)d_in[15];
  const float* out_b      = (const float*)d_in[16];

  float* ws = (float*)d_ws;
  float* qo   = ws;                 // [3][4096][10]
  float* ko   = ws + 122880;        // [3][4096][10]
  float* vo   = ws + 245760;        // [3][4096][10]
  float* hn   = ws + 368640;        // [4096][30]
  float* part = ws + 491520;        // [3][4096][NS][12]

  const size_t need16 = ((size_t)491520 + (size_t)3*4096*16*12) * 4;
  const int NS = (ws_size >= need16) ? 16 : 8;

  lstm_k<<<Bsz/16, 128, 0, stream>>>(input, w_ih, w_hh, b_ih, b_hh,
                                     in_proj_w, in_proj_b, qo, ko, vo, hn);
  attn_part<<<dim3(Bsz/256, 3, NS), 256, 0, stream>>>(qo, ko, vo, part, Bsz/NS);
  tail_k<<<Bsz/4, 256, 0, stream>>>(part, NS, hn, out_proj_w, out_proj_b,
                                    fc1_w, fc1_b, fc2_w, fc2_b,
                                    ln_g, ln_b, out_w, out_b, (float*)d_out);
}